// Round 7
// baseline (640.471 us; speedup 1.0000x reference)
//
#include <hip/hip_runtime.h>

// Problem constants
#define DD 128    // nodes / input dim
#define HH 512    // hidden
#define NN 2048   // batch rows
#define NT 64     // rows per block tile
#define PLD 516   // pack LDS leading dim

typedef __bf16 bf16x8 __attribute__((ext_vector_type(8)));
typedef __bf16 bf16x4 __attribute__((ext_vector_type(4)));
typedef float  floatx4 __attribute__((ext_vector_type(4)));

// ---------------------------------------------------------------------------
// x (fp32 row-major) -> xb (bf16 row-major). 2048x128, 16B/thread.
// ---------------------------------------------------------------------------
__global__ void cvt_x(const float* __restrict__ x, __bf16* __restrict__ xb) {
    int t = blockIdx.x * blockDim.x + threadIdx.x;
    float4 v = *(const float4*)(x + (size_t)t * 4);
    bf16x4 o;
    o[0] = (__bf16)v.x; o[1] = (__bf16)v.y; o[2] = (__bf16)v.z; o[3] = (__bf16)v.w;
    *(bf16x4*)(xb + (size_t)t * 4) = o;
}

// ---------------------------------------------------------------------------
// Pack W[d][K][H] fp32 -> bf16 16x16x32-MFMA fragment order via LDS transpose.
//   Wp[((((d*32+ct)*nks+ks)*4+q)*16+c)*8+j] = bf16(W[d][ks*32+q*8+j][ct*16+c])
// Serves as A-frag of W^T (A[m][k]=W[k][m]) for the transposed-operand MFMA.
// ---------------------------------------------------------------------------
__global__ void pack_w(const float* __restrict__ W, __bf16* __restrict__ Wp, int nks) {
    __shared__ __bf16 Ls[32 * PLD];
    const int d  = blockIdx.x / nks;
    const int ks = blockIdx.x % nks;
    const int tid = threadIdx.x;
    const float* src = W + ((size_t)(d * nks + ks) * 32) * HH;

#pragma unroll
    for (int it = 0; it < 16; ++it) {
        int e = (it * 256 + tid) * 4;
        float4 v = *(const float4*)(src + e);
        bf16x4 o;
        o[0] = (__bf16)v.x; o[1] = (__bf16)v.y; o[2] = (__bf16)v.z; o[3] = (__bf16)v.w;
        *(bf16x4*)(Ls + (e >> 9) * PLD + (e & 511)) = o;
    }
    __syncthreads();

#pragma unroll
    for (int it = 0; it < 8; ++it) {
        int ch = it * 256 + tid;
        int c  = ch & 15;
        int q  = (ch >> 4) & 3;
        int ct = ch >> 6;
        bf16x8 v;
#pragma unroll
        for (int j = 0; j < 8; ++j)
            v[j] = Ls[(q * 8 + j) * PLD + ct * 16 + c];
        *(bf16x8*)(Wp + ((size_t)(d * 32 + ct) * nks + ks) * 512 + (ch & 63) * 8) = v;
    }
}

// ---------------------------------------------------------------------------
// Fused per-(d, row-tile) MLP, transposed operand order (16x16x32 bf16 —
// round-6 showed 32x32x16 loses ILP at equal operand bandwidth):
//   mfma(Wfrag, Xfrag) => D = (X.W)^T: lane lc holds output ROW, 4 consecutive
//   cols per reg group -> h1 stores are ds_write_b64.
// TWO ROW-PASSES of 32: acc = 32 AGPR (was 64), freeing ~60 VGPRs under the
// (512,4) 128-reg cap so the compiler can prefetch next-ks wf/hf fragments
// (round-5 had 12 spare regs -> no pipelining -> every pipe ~35% busy,
// latency-bound). W1 fragments are re-read once more per block (L2-resident).
// Per-wave k-start STAGGER (+4w mod 16) decorrelates the 8 waves' L2 bursts.
// h1s: 64x512 bf16, 16B chunks XOR-swizzled by row&7.
// ---------------------------------------------------------------------------
__launch_bounds__(512, 4)
__global__ void grandag_main(const __bf16* __restrict__ xb,
                             const __bf16* __restrict__ W0p,
                             const __bf16* __restrict__ W1p,
                             const float* __restrict__ W2,
                             float* __restrict__ out) {
    __shared__ __bf16 h1s[NT * HH];   // 65536 B
    __shared__ float  outp[NT];       // -> 2 blocks/CU

    const int b  = blockIdx.x;
    // XCD swizzle: d % 8 == blockIdx % 8 -> all 32 tiles of a d on one XCD
    const int d  = ((b >> 8) << 3) | (b & 7);
    const int n0 = ((b >> 3) & 31) * NT;

    const int tid = threadIdx.x;
    const int w   = tid >> 6;   // wave 0..7: owns h-cols [w*64, w*64+64)
    const int l   = tid & 63;
    const int lc  = l & 15;     // C/D col = batch row (transposed form)
    const int lq  = l >> 4;     // k-quad
    const int sw  = lc & 7;     // LDS swizzle key (row-derived)
    const int lane16 = lq * 16 + lc;   // per-lane frag index (8-elem units)

    const int ksz = d >> 5;          // k-slice containing column d of X
    const int lqz = (d >> 3) & 3;    // quad containing it
    const int jz  = d & 7;           // element containing it

    if (tid < NT) outp[tid] = 0.f;

    // ---- phase 1: h1 = leaky(W0[d]^T . Xmask^T), two row-passes of 32
    {
        const __bf16* W0b = W0p + ((size_t)(d * 32 + w * 4) * 4) * 512 + (size_t)lane16 * 8;
        const __bf16* xbb = xb + (size_t)(n0 + lc) * DD + lq * 8;
#pragma unroll
        for (int pass = 0; pass < 2; pass++) {
            floatx4 acc[4][2] = {};
#pragma unroll
            for (int ks = 0; ks < 4; ks++) {
                const int kss = (ks + w) & 3;     // per-wave k stagger
                bf16x8 wf[4];
#pragma unroll
                for (int mt = 0; mt < 4; mt++)
                    wf[mt] = *(const bf16x8*)(W0b + (size_t)(mt * 4 + kss) * 512);
                const bool domask = (kss == ksz) && (lq == lqz);
#pragma unroll
                for (int nt = 0; nt < 2; nt++) {
                    bf16x8 xf = *(const bf16x8*)(xbb + (size_t)(16 * (2 * pass + nt)) * DD + kss * 32);
                    if (domask) {
#pragma unroll
                        for (int j = 0; j < 8; j++)
                            if (j == jz) xf[j] = (__bf16)0.f;
                    }
#pragma unroll
                    for (int mt = 0; mt < 4; mt++)
                        acc[mt][nt] = __builtin_amdgcn_mfma_f32_16x16x32_bf16(
                            wf[mt], xf, acc[mt][nt], 0, 0, 0);
                }
            }
            // epilogue: lane holds h1[row=16(2p+nt)+lc][col=64w+16mt+4lq+g]
#pragma unroll
            for (int mt = 0; mt < 4; mt++) {
                const int chunk = 8 * w + 2 * mt + (lq >> 1);
#pragma unroll
                for (int nt = 0; nt < 2; nt++) {
                    bf16x4 o;
#pragma unroll
                    for (int g = 0; g < 4; g++) {
                        float v = acc[mt][nt][g];
                        o[g] = (__bf16)fmaxf(v, 0.01f * v);   // leaky relu
                    }
                    *(bf16x4*)(h1s + (16 * (2 * pass + nt) + lc) * HH +
                               ((chunk ^ sw) << 3) + ((lq & 1) << 2)) = o;
                }
            }
        }
    }
    __syncthreads();

    // ---- phases 2+3 fused, two row-passes of 32:
    //      acc2 = W1[d]^T . h1^T ; out += leaky(acc2)^T . W2
    {
        const __bf16* W1b = W1p + ((size_t)(d * 32 + w * 4) * 16) * 512 + (size_t)lane16 * 8;
        const __bf16* h1b = h1s + lc * HH;
        const float*  W2b = W2 + (size_t)d * HH + w * 64 + lq * 4;
#pragma unroll
        for (int pass = 0; pass < 2; pass++) {
            floatx4 acc2[4][2] = {};
#pragma unroll
            for (int ks = 0; ks < 16; ks++) {
                const int kss = (ks + 4 * w) & 15;   // per-wave k stagger
                bf16x8 wf[4];
#pragma unroll
                for (int mt = 0; mt < 4; mt++)
                    wf[mt] = *(const bf16x8*)(W1b + (size_t)(mt * 16 + kss) * 512);
                const int hoff = ((4 * kss + lq) ^ sw) << 3;
#pragma unroll
                for (int nt = 0; nt < 2; nt++) {
                    bf16x8 hf = *(const bf16x8*)(h1b + (size_t)(16 * (2 * pass + nt)) * HH + hoff);
#pragma unroll
                    for (int mt = 0; mt < 4; mt++)
                        acc2[mt][nt] = __builtin_amdgcn_mfma_f32_16x16x32_bf16(
                            wf[mt], hf, acc2[mt][nt], 0, 0, 0);
                }
            }
            // phase 3: lane lc holds rows 16(2p+nt)+lc
#pragma unroll
            for (int nt = 0; nt < 2; nt++) {
                float s = 0.f;
#pragma unroll
                for (int mt = 0; mt < 4; mt++) {
                    floatx4 w2q = *(const floatx4*)(W2b + mt * 16);
#pragma unroll
                    for (int g = 0; g < 4; g++) {
                        float v = acc2[mt][nt][g];
                        s += fmaxf(v, 0.01f * v) * w2q[g];
                    }
                }
                s += __shfl_xor(s, 16, 64);
                s += __shfl_xor(s, 32, 64);
                if (l < 16) atomicAdd(&outp[16 * (2 * pass + nt) + lc], s);
            }
        }
    }
    __syncthreads();
    if (tid < NT) out[(size_t)(n0 + tid) * DD + d] = outp[tid];
}

// ---------------------------------------------------------------------------
extern "C" void kernel_launch(void* const* d_in, const int* in_sizes, int n_in,
                              void* d_out, int out_size, void* d_ws, size_t ws_size,
                              hipStream_t stream) {
    const float* x  = (const float*)d_in[0];
    const float* W0 = (const float*)d_in[1];
    const float* W1 = (const float*)d_in[2];
    const float* W2 = (const float*)d_in[3];
    float* out = (float*)d_out;

    __bf16* W0p = (__bf16*)d_ws;                                          // 16.8 MB
    __bf16* W1p = (__bf16*)((char*)d_ws + (size_t)DD * DD * HH * 2);      // 67.1 MB
    __bf16* xb  = (__bf16*)((char*)d_ws + (size_t)DD * DD * HH * 2
                                        + (size_t)DD * HH * HH * 2);      // 0.5 MB

    cvt_x<<<dim3(NN * DD / (256 * 4)), 256, 0, stream>>>(x, xb);
    pack_w<<<dim3(DD * (DD / 32)), 256, 0, stream>>>(W0, W0p, DD / 32);   // 512 blocks
    pack_w<<<dim3(DD * (HH / 32)), 256, 0, stream>>>(W1, W1p, HH / 32);   // 2048 blocks

    grandag_main<<<dim3(DD * (NN / NT)), 512, 0, stream>>>(xb, W0p, W1p, W2, out);
}